// Round 3
// baseline (289.737 us; speedup 1.0000x reference)
//
#include <hip/hip_runtime.h>
#include <cstdint>
#include <cstddef>

typedef unsigned short u16;
typedef unsigned int u32;
typedef __bf16 bf16x8 __attribute__((ext_vector_type(8)));
typedef float f32x4 __attribute__((ext_vector_type(4)));

static constexpr int CDIM = 768;
static constexpr int NROWS = 8192;   // B*Lq == B*H*W

__device__ __forceinline__ u16 f2bf(float f) {
  union { float f; u32 u; } v; v.f = f;
  return (u16)((v.u + 0x7fffu + ((v.u >> 16) & 1u)) >> 16);   // RNE
}
__device__ __forceinline__ float bf2f(u16 h) {
  union { u32 u; float f; } v; v.u = ((u32)h) << 16;
  return v.f;
}
// Load element i of an external tensor whose dtype is runtime-detected:
// F=1 -> float32, F=0 -> bf16.
__device__ __forceinline__ float ldf(const void* p, size_t i, int F) {
  return F ? ((const float*)p)[i] : bf2f(((const u16*)p)[i]);
}

// ---------------- dtype detection: bf16 NaN/Inf bit patterns in f32-viewed-as-u16 ----------------
__global__ __launch_bounds__(256) void detect_kernel(const u16* __restrict__ x, int* __restrict__ flag) {
  int t = threadIdx.x;
  int cnt = 0;
  for (int i = t; i < 16384; i += 256) {
    u16 v = x[i];
    if ((v & 0x7F80u) == 0x7F80u) cnt++;   // bf16 exponent all-ones => NaN/Inf pattern
  }
  #pragma unroll
  for (int m = 32; m >= 1; m >>= 1) cnt += __shfl_xor(cnt, m, 64);
  __shared__ int r[4];
  if ((t & 63) == 0) r[t >> 6] = cnt;
  __syncthreads();
  if (t == 0) flag[0] = (r[0] + r[1] + r[2] + r[3] > 4) ? 1 : 0;   // 1 = inputs are f32
}

// ---------------- fused LayerNorm (x -> q_bf, feat -> f_bf), one block per row ----------------
__global__ __launch_bounds__(256) void ln_kernel(
    const void* __restrict__ x, const void* __restrict__ feat,
    const void* __restrict__ qw, const void* __restrict__ qb,
    const void* __restrict__ fw, const void* __restrict__ fb,
    u16* __restrict__ qout, u16* __restrict__ fout, const int* __restrict__ flagp) {
  const int F = *flagp;
  int row = blockIdx.x;   // 0..16383
  const void *src, *w, *b; u16* dst; size_t base;
  if (row < NROWS) { src = x; base = (size_t)row*CDIM; w = qw; b = qb; dst = qout + base; }
  else { int r2 = row - NROWS; src = feat; base = (size_t)r2*CDIM; w = fw; b = fb; dst = fout + (size_t)r2*CDIM; }
  int t = threadIdx.x;
  float v0 = ldf(src, base+t, F), v1 = ldf(src, base+t+256, F), v2 = ldf(src, base+t+512, F);
  float s = v0+v1+v2, sq = v0*v0+v1*v1+v2*v2;
  #pragma unroll
  for (int m = 32; m >= 1; m >>= 1) { s += __shfl_xor(s, m, 64); sq += __shfl_xor(sq, m, 64); }
  __shared__ float red[8];
  int lane = t & 63, wv = t >> 6;
  if (lane == 0) { red[wv] = s; red[wv+4] = sq; }
  __syncthreads();
  s  = red[0]+red[1]+red[2]+red[3];
  sq = red[4]+red[5]+red[6]+red[7];
  float mean = s * (1.f/768.f);
  float var  = fmaxf(sq * (1.f/768.f) - mean*mean, 0.f);
  float inv  = rsqrtf(var + 1e-6f);
  dst[t]     = f2bf((v0-mean)*inv*ldf(w,t,F)     + ldf(b,t,F));
  dst[t+256] = f2bf((v1-mean)*inv*ldf(w,t+256,F) + ldf(b,t+256,F));
  dst[t+512] = f2bf((v2-mean)*inv*ldf(w,t+512,F) + ldf(b,t+512,F));
}

// ---------------- transpose weights [K=768][N=768] -> [N][K], converting to bf16 ----------------
__global__ __launch_bounds__(256) void transpose_wt(
    const void* __restrict__ wv_, const void* __restrict__ wo_,
    u16* __restrict__ wvT, u16* __restrict__ woT, const int* __restrict__ flagp) {
  const int F = *flagp;
  __shared__ u16 tile[32][33];
  const void* in = blockIdx.z ? wo_ : wv_;
  u16* out       = blockIdx.z ? woT : wvT;
  int bn = blockIdx.x * 32;   // input col (n) base
  int bk = blockIdx.y * 32;   // input row (k) base
  int tx = threadIdx.x & 31, ty = threadIdx.x >> 5;
  #pragma unroll
  for (int i = ty; i < 32; i += 8)
    tile[i][tx] = F ? f2bf(((const float*)in)[(size_t)(bk+i)*CDIM + bn + tx])
                    : ((const u16*)in)[(size_t)(bk+i)*CDIM + bn + tx];
  __syncthreads();
  #pragma unroll
  for (int i = ty; i < 32; i += 8)
    out[(size_t)(bn+i)*CDIM + bk + tx] = tile[tx][i];
}

// ---------------- build padded [128][768] B^T for [w_off | w_attn | 0], bf16 ----------------
__global__ __launch_bounds__(256) void build_woffaw(
    const void* __restrict__ woff, const void* __restrict__ wattn, u16* __restrict__ outT,
    const int* __restrict__ flagp) {
  const int F = *flagp;
  int idx = blockIdx.x * 256 + threadIdx.x;
  if (idx >= 128 * CDIM) return;
  int n = idx / CDIM, k = idx - n*CDIM;
  float v = 0.f;
  if (n < 48)      v = ldf(woff, (size_t)k*48 + n, F);
  else if (n < 72) v = ldf(wattn, (size_t)k*24 + (n-48), F);
  outT[idx] = f2bf(v);
}

// ---------------- MFMA GEMM: C[M,N] = A[M,768] * Bt[N,768]^T, 128x128 tile ----------------
// EPI 0: bf16 store + bias0            (value projection)
// EPI 1: f32 store to [M][72], bias0(48)=b_off, bias1(24)=b_attn (off/attn projection)
// EPI 2: store out = x + gamma*(acc + bias0) in detected dtype   (output projection)
template<int EPI>
__global__ __launch_bounds__(256) void gemm_bt(
    const u16* __restrict__ A, const u16* __restrict__ Bt,
    void* __restrict__ Cout,
    const void* __restrict__ bias0, const void* __restrict__ bias1,
    const void* __restrict__ xres, const void* __restrict__ gamma,
    const int* __restrict__ flagp) {
  const int F = *flagp;
  __shared__ __align__(16) u16 As[128*32];
  __shared__ __align__(16) u16 Bs[128*32];
  const int m0 = blockIdx.x * 128;
  const int n0 = blockIdx.y * 128;
  const int t = threadIdx.x;
  const int lane = t & 63;
  const int wv = t >> 6;
  const int wm = wv & 1, wn = wv >> 1;
  f32x4 acc[4][4] = {};

  for (int k0 = 0; k0 < CDIM; k0 += 32) {
    #pragma unroll
    for (int j = 0; j < 2; ++j) {
      const int offh = t*8 + j*2048;       // ushort offset into 128x32 tile
      const int row  = offh >> 5;          // tile row (32 ushorts per row)
      const int col  = offh & 31;
      *(bf16x8*)(As + offh) = *(const bf16x8*)(A  + (size_t)(m0+row)*CDIM + k0 + col);
      *(bf16x8*)(Bs + offh) = *(const bf16x8*)(Bt + (size_t)(n0+row)*CDIM + k0 + col);
    }
    __syncthreads();
    bf16x8 af[4], bfr[4];
    #pragma unroll
    for (int i = 0; i < 4; ++i)
      af[i]  = *(const bf16x8*)(As + ((wm*64 + i*16 + (lane & 15))*32 + (lane >> 4)*8));
    #pragma unroll
    for (int i = 0; i < 4; ++i)
      bfr[i] = *(const bf16x8*)(Bs + ((wn*64 + i*16 + (lane & 15))*32 + (lane >> 4)*8));
    #pragma unroll
    for (int mt = 0; mt < 4; ++mt)
      #pragma unroll
      for (int nt = 0; nt < 4; ++nt)
        acc[mt][nt] = __builtin_amdgcn_mfma_f32_16x16x32_bf16(af[mt], bfr[nt], acc[mt][nt], 0, 0, 0);
    __syncthreads();
  }

  const int r0 = (lane >> 4) * 4;   // C/D: col=lane&15, row=(lane>>4)*4+reg  [m89/m91]
  const int c  = lane & 15;
  #pragma unroll
  for (int mt = 0; mt < 4; ++mt) {
    #pragma unroll
    for (int nt = 0; nt < 4; ++nt) {
      const int col = n0 + wn*64 + nt*16 + c;
      #pragma unroll
      for (int r = 0; r < 4; ++r) {
        const int row = m0 + wm*64 + mt*16 + r0 + r;
        float v = acc[mt][nt][r];
        if (EPI == 0) {
          ((u16*)Cout)[(size_t)row*CDIM + col] = f2bf(v + ldf(bias0, col, F));
        } else if (EPI == 1) {
          if (col < 72) {
            float bb = (col < 48) ? ldf(bias0, col, F) : ldf(bias1, col-48, F);
            ((float*)Cout)[(size_t)row*72 + col] = v + bb;
          }
        } else {
          size_t idx = (size_t)row*CDIM + col;
          float o = ldf(xres, idx, F) + ldf(gamma, col, F) * (v + ldf(bias0, col, F));
          if (F) ((float*)Cout)[idx] = o;
          else   ((u16*)Cout)[idx]   = f2bf(o);
        }
      }
    }
  }
}

// ---------------- deformable sampling: one wave per (b,q,h), lane covers 2 of 128 dims ----------------
__global__ __launch_bounds__(256) void sample_kernel(
    const u16* __restrict__ value,   // [B*4096][768] bf16, col = h*128+d
    const float* __restrict__ offaw, // [8192][72] f32: 0..47 off (h*8+p*2+c), 48..71 aw (48+h*4+p)
    const void* __restrict__ refp,   // [8192][2] external dtype
    u16* __restrict__ out, const int* __restrict__ flagp) {  // [8192][768] bf16
  const int F = *flagp;
  const int wid  = blockIdx.x * 4 + (threadIdx.x >> 6);  // 0..49151
  const int lane = threadIdx.x & 63;
  const int h   = wid % 6;
  const int row = wid / 6;        // b*4096 + q
  const int b   = row >> 12;
  const float* ob = offaw + (size_t)row*72 + h*8;
  const float* ab = offaw + (size_t)row*72 + 48 + h*4;
  float rx = ldf(refp, (size_t)row*2,   F) * 64.f - 0.5f;
  float ry = ldf(refp, (size_t)row*2+1, F) * 64.f - 0.5f;
  float a0 = ab[0], a1 = ab[1], a2 = ab[2], a3 = ab[3];
  float mx = fmaxf(fmaxf(a0,a1), fmaxf(a2,a3));
  float e0 = __expf(a0-mx), e1 = __expf(a1-mx), e2 = __expf(a2-mx), e3 = __expf(a3-mx);
  float rs = 1.f / (e0+e1+e2+e3);
  float awt[4] = {e0*rs, e1*rs, e2*rs, e3*rs};
  const u32* vb = (const u32*)value + (size_t)b*4096*384 + h*64 + lane;
  float accx = 0.f, accy = 0.f;
  #pragma unroll
  for (int p = 0; p < 4; ++p) {
    float px = rx + ob[p*2];
    float py = ry + ob[p*2+1];
    float x0f = floorf(px), y0f = floorf(py);
    float fx = px - x0f, fy = py - y0f;
    int x0 = (int)x0f, y0 = (int)y0f;
    #pragma unroll
    for (int dy = 0; dy < 2; ++dy) {
      #pragma unroll
      for (int dx = 0; dx < 2; ++dx) {
        int yi = y0 + dy, xi = x0 + dx;
        float wt = (dy ? fy : 1.f-fy) * (dx ? fx : 1.f-fx) * awt[p];
        if (yi < 0 || yi >= 64 || xi < 0 || xi >= 64) wt = 0.f;
        if (wt != 0.f) {                      // wave-uniform branch
          u32 v = vb[(size_t)(yi*64 + xi) * 384];
          accx += wt * bf2f((u16)(v & 0xffffu));
          accy += wt * bf2f((u16)(v >> 16));
        }
      }
    }
  }
  ((u32*)out)[(size_t)row*384 + h*64 + lane] = (u32)f2bf(accx) | ((u32)f2bf(accy) << 16);
}

extern "C" void kernel_launch(void* const* d_in, const int* in_sizes, int n_in,
                              void* d_out, int out_size, void* d_ws, size_t ws_size,
                              hipStream_t stream) {
  const void* x       = d_in[0];
  const void* refp    = d_in[1];
  const void* feat    = d_in[2];
  // d_in[3] spatial_shapes (int32), d_in[4] level_start_index (int32): constants here
  const void* qn_w    = d_in[5];
  const void* qn_b    = d_in[6];
  const void* fn_w    = d_in[7];
  const void* fn_b    = d_in[8];
  const void* gamma   = d_in[9];
  const void* w_value = d_in[10];
  const void* b_value = d_in[11];
  const void* w_off   = d_in[12];
  const void* b_off   = d_in[13];
  const void* w_attn  = d_in[14];
  const void* b_attn  = d_in[15];
  const void* w_out   = d_in[16];
  const void* b_out   = d_in[17];

  char* p = (char*)d_ws;
  const size_t act = (size_t)NROWS * CDIM * 2;       // 12.58 MB
  u16* q_bf   = (u16*)p; p += act;
  u16* f_bf   = (u16*)p; p += act;
  u16* val_bf = (u16*)p; p += act;
  u16* wvT    = (u16*)p; p += (size_t)CDIM*CDIM*2;
  u16* woT    = (u16*)p; p += (size_t)CDIM*CDIM*2;
  u16* woaT   = (u16*)p; p += (size_t)128*CDIM*2;
  float* offaw = (float*)p; p += (size_t)NROWS*72*4;
  int* dflag  = (int*)p; p += 256;
  u16* samp_bf = q_bf;   // q_bf dead after gemm_bt<1>; reuse for sampled output

  detect_kernel<<<dim3(1), 256, 0, stream>>>((const u16*)x, dflag);
  transpose_wt<<<dim3(24,24,2), 256, 0, stream>>>(w_value, w_out, wvT, woT, dflag);
  build_woffaw<<<dim3(384), 256, 0, stream>>>(w_off, w_attn, woaT, dflag);
  ln_kernel<<<dim3(16384), 256, 0, stream>>>(x, feat, qn_w, qn_b, fn_w, fn_b, q_bf, f_bf, dflag);
  gemm_bt<0><<<dim3(64,6), 256, 0, stream>>>(f_bf, wvT, val_bf, b_value, nullptr, nullptr, nullptr, dflag);
  gemm_bt<1><<<dim3(64,1), 256, 0, stream>>>(q_bf, woaT, offaw, b_off, b_attn, nullptr, nullptr, dflag);
  sample_kernel<<<dim3(12288), 256, 0, stream>>>(val_bf, offaw, refp, samp_bf, dflag);
  gemm_bt<2><<<dim3(64,6), 256, 0, stream>>>(samp_bf, woT, d_out, b_out, nullptr, x, gamma, dflag);
}

// Round 4
// 252.455 us; speedup vs baseline: 1.1477x; 1.1477x over previous
//
#include <hip/hip_runtime.h>
#include <cstdint>
#include <cstddef>

typedef unsigned short u16;
typedef unsigned int u32;
typedef __bf16 bf16x8 __attribute__((ext_vector_type(8)));
typedef float f32x4 __attribute__((ext_vector_type(4)));

static constexpr int CDIM = 768;
static constexpr int NROWS = 8192;   // B*Lq == B*H*W
static constexpr int ASTR = 72;      // padded LDS row stride (u16) for A/B tiles

__device__ __forceinline__ u16 f2bf(float f) {
  union { float f; u32 u; } v; v.f = f;
  return (u16)((v.u + 0x7fffu + ((v.u >> 16) & 1u)) >> 16);   // RNE
}
__device__ __forceinline__ float bf2f(u16 h) {
  union { u32 u; float f; } v; v.u = ((u32)h) << 16;
  return v.f;
}
// Load element i of an external tensor whose dtype is runtime-detected: F=1 f32, F=0 bf16.
__device__ __forceinline__ float ldf(const void* p, size_t i, int F) {
  return F ? ((const float*)p)[i] : bf2f(((const u16*)p)[i]);
}

// ---------------- dtype detection ----------------
__global__ __launch_bounds__(256) void detect_kernel(const u16* __restrict__ x, int* __restrict__ flag) {
  int t = threadIdx.x;
  int cnt = 0;
  for (int i = t; i < 16384; i += 256) {
    u16 v = x[i];
    if ((v & 0x7F80u) == 0x7F80u) cnt++;   // bf16 NaN/Inf pattern
  }
  #pragma unroll
  for (int m = 32; m >= 1; m >>= 1) cnt += __shfl_xor(cnt, m, 64);
  __shared__ int r[4];
  if ((t & 63) == 0) r[t >> 6] = cnt;
  __syncthreads();
  if (t == 0) flag[0] = (r[0] + r[1] + r[2] + r[3] > 4) ? 1 : 0;   // 1 = f32 inputs
}

// ---------------- fused LayerNorm, vectorized: 192 threads, one row/block ----------------
__global__ __launch_bounds__(192) void ln_kernel(
    const void* __restrict__ x, const void* __restrict__ feat,
    const void* __restrict__ qw, const void* __restrict__ qb,
    const void* __restrict__ fw, const void* __restrict__ fb,
    u16* __restrict__ qout, u16* __restrict__ fout, const int* __restrict__ flagp) {
  const int F = *flagp;
  int row = blockIdx.x;   // 0..16383
  const void *src, *w, *b; u16* dst; size_t base;
  if (row < NROWS) { src = x; base = (size_t)row*CDIM; w = qw; b = qb; dst = qout + base; }
  else { int r2 = row - NROWS; src = feat; base = (size_t)r2*CDIM; w = fw; b = fb; dst = fout + (size_t)r2*CDIM; }
  int t = threadIdx.x;     // 0..191, covers 4 elems each
  float v[4];
  if (F) {
    float4 q = ((const float4*)((const float*)src + base))[t];
    v[0]=q.x; v[1]=q.y; v[2]=q.z; v[3]=q.w;
  } else {
    const u16* sp = (const u16*)src + base + t*4;
    v[0]=bf2f(sp[0]); v[1]=bf2f(sp[1]); v[2]=bf2f(sp[2]); v[3]=bf2f(sp[3]);
  }
  float s = v[0]+v[1]+v[2]+v[3];
  float sq = v[0]*v[0]+v[1]*v[1]+v[2]*v[2]+v[3]*v[3];
  #pragma unroll
  for (int m = 32; m >= 1; m >>= 1) { s += __shfl_xor(s, m, 64); sq += __shfl_xor(sq, m, 64); }
  __shared__ float red[6];
  int lane = t & 63, wv = t >> 6;
  if (lane == 0) { red[wv] = s; red[wv+3] = sq; }
  __syncthreads();
  s  = red[0]+red[1]+red[2];
  sq = red[3]+red[4]+red[5];
  float mean = s * (1.f/768.f);
  float var  = fmaxf(sq * (1.f/768.f) - mean*mean, 0.f);
  float inv  = rsqrtf(var + 1e-6f);
  u16 o[4];
  #pragma unroll
  for (int k = 0; k < 4; ++k) {
    float wk = ldf(w, t*4+k, F), bk = ldf(b, t*4+k, F);
    o[k] = f2bf((v[k]-mean)*inv*wk + bk);
  }
  *(ushort4*)(dst + t*4) = make_ushort4(o[0], o[1], o[2], o[3]);
}

// ---------------- transpose weights [K=768][N=768] -> [N][K], to bf16 ----------------
__global__ __launch_bounds__(256) void transpose_wt(
    const void* __restrict__ wv_, const void* __restrict__ wo_,
    u16* __restrict__ wvT, u16* __restrict__ woT, const int* __restrict__ flagp) {
  const int F = *flagp;
  __shared__ u16 tile[32][33];
  const void* in = blockIdx.z ? wo_ : wv_;
  u16* out       = blockIdx.z ? woT : wvT;
  int bn = blockIdx.x * 32;
  int bk = blockIdx.y * 32;
  int tx = threadIdx.x & 31, ty = threadIdx.x >> 5;
  #pragma unroll
  for (int i = ty; i < 32; i += 8)
    tile[i][tx] = F ? f2bf(((const float*)in)[(size_t)(bk+i)*CDIM + bn + tx])
                    : ((const u16*)in)[(size_t)(bk+i)*CDIM + bn + tx];
  __syncthreads();
  #pragma unroll
  for (int i = ty; i < 32; i += 8)
    out[(size_t)(bn+i)*CDIM + bk + tx] = tile[tx][i];
}

// ---------------- build padded [128][768] B^T for [w_off | w_attn | 0], bf16 ----------------
__global__ __launch_bounds__(256) void build_woffaw(
    const void* __restrict__ woff, const void* __restrict__ wattn, u16* __restrict__ outT,
    const int* __restrict__ flagp) {
  const int F = *flagp;
  int idx = blockIdx.x * 256 + threadIdx.x;
  if (idx >= 128 * CDIM) return;
  int n = idx / CDIM, k = idx - n*CDIM;
  float v = 0.f;
  if (n < 48)      v = ldf(woff, (size_t)k*48 + n, F);
  else if (n < 72) v = ldf(wattn, (size_t)k*24 + (n-48), F);
  outT[idx] = f2bf(v);
}

// ---------------- MFMA GEMM: C[M,N] = A[M,768]*Bt[N,768]^T, tile 128x64, BK=64 ----------------
// grid (M/128, N/64, KS).  EPI 0: bf16 C+bias.  EPI 1: f32 K-partials [z][M][72], bias in z==0.
// EPI 2: out = x + gamma*(C + bias), dtype per flag.
template<int EPI>
__global__ __launch_bounds__(256) void gemm_bt(
    const u16* __restrict__ A, const u16* __restrict__ Bt, void* __restrict__ Cout,
    const void* __restrict__ bias0, const void* __restrict__ bias1,
    const void* __restrict__ xres, const void* __restrict__ gammap,
    const int* __restrict__ flagp) {
  const int F = *flagp;
  __shared__ __align__(16) u16 smem[(128+64)*ASTR];   // 27.6 KB; Cs aliases As region
  u16* As = smem;              // [128][ASTR]
  u16* Bs = smem + 128*ASTR;   // [64][ASTR]
  u16* Cs = smem;              // [128][64] epilogue staging (fits in As region)
  const int m0 = blockIdx.x * 128;
  const int n0 = blockIdx.y * 64;
  const int t = threadIdx.x, lane = t & 63, wv = t >> 6;
  const int wm = wv & 1, wn = wv >> 1;
  const int kChunk = CDIM / gridDim.z;
  const int kbase = blockIdx.z * kChunk;
  const int lr = lane >> 3;          // staging row-in-segment
  const int lc = (lane & 7) * 8;     // staging col (u16)
  f32x4 acc[4][2] = {};

  for (int kk = 0; kk < kChunk; kk += 64) {
    const int k0 = kbase + kk;
    #pragma unroll
    for (int j = 0; j < 4; ++j) {                  // A: 16 segments of 8 rows
      int row = (wv*4 + j)*8 + lr;
      *(bf16x8*)(As + row*ASTR + lc) = *(const bf16x8*)(A + (size_t)(m0+row)*CDIM + k0 + lc);
    }
    #pragma unroll
    for (int j = 0; j < 2; ++j) {                  // B: 8 segments of 8 rows
      int row = (wv*2 + j)*8 + lr;
      *(bf16x8*)(Bs + row*ASTR + lc) = *(const bf16x8*)(Bt + (size_t)(n0+row)*CDIM + k0 + lc);
    }
    __syncthreads();
    #pragma unroll
    for (int u = 0; u < 2; ++u) {
      bf16x8 af[4], bfr[2];
      const int kc = u*32 + (lane >> 4)*8;
      #pragma unroll
      for (int i = 0; i < 4; ++i)
        af[i]  = *(const bf16x8*)(As + (wm*64 + i*16 + (lane & 15))*ASTR + kc);
      #pragma unroll
      for (int j = 0; j < 2; ++j)
        bfr[j] = *(const bf16x8*)(Bs + (wn*32 + j*16 + (lane & 15))*ASTR + kc);
      #pragma unroll
      for (int i = 0; i < 4; ++i)
        #pragma unroll
        for (int j = 0; j < 2; ++j)
          acc[i][j] = __builtin_amdgcn_mfma_f32_16x16x32_bf16(af[i], bfr[j], acc[i][j], 0, 0, 0);
    }
    __syncthreads();
  }

  const int r0 = (lane >> 4) * 4;    // C/D: col=lane&15, row=(lane>>4)*4+reg  [m89/m91]
  const int c  = lane & 15;

  if (EPI == 1) {                    // direct scattered f32 partial stores (only 72 cols live)
    float* op = (float*)Cout + (size_t)blockIdx.z * NROWS * 72;
    #pragma unroll
    for (int i = 0; i < 4; ++i)
      #pragma unroll
      for (int j = 0; j < 2; ++j) {
        int col = n0 + wn*32 + j*16 + c;
        if (col < 72) {
          float bb = 0.f;
          if (blockIdx.z == 0) bb = (col < 48) ? ldf(bias0, col, F) : ldf(bias1, col-48, F);
          #pragma unroll
          for (int r = 0; r < 4; ++r)
            op[(size_t)(m0 + wm*64 + i*16 + r0 + r)*72 + col] = acc[i][j][r] + bb;
        }
      }
    return;
  }

  // stage (acc + bias) as bf16 into Cs, then coalesced stores
  #pragma unroll
  for (int i = 0; i < 4; ++i)
    #pragma unroll
    for (int j = 0; j < 2; ++j) {
      int col = wn*32 + j*16 + c;
      float bb = ldf(bias0, n0 + col, F);
      #pragma unroll
      for (int r = 0; r < 4; ++r)
        Cs[(wm*64 + i*16 + r0 + r)*64 + col] = f2bf(acc[i][j][r] + bb);
    }
  __syncthreads();
  #pragma unroll
  for (int it = 0; it < 4; ++it) {
    int idx = it*256 + t;            // 0..1023, 16B each -> 128x64 u16 tile
    int row = idx >> 3, colb = (idx & 7) * 8;
    size_t gbase = (size_t)(m0 + row)*CDIM + n0 + colb;
    const u16* cp = Cs + row*64 + colb;
    if (EPI == 0) {
      *(bf16x8*)((u16*)Cout + gbase) = *(const bf16x8*)cp;
    } else {                          // EPI 2
      if (F) {
        const float* xp = (const float*)xres + gbase;
        const float* gp = (const float*)gammap + n0 + colb;
        float4 x0 = *(const float4*)xp,      x1 = *(const float4*)(xp + 4);
        float4 g0 = *(const float4*)gp,      g1 = *(const float4*)(gp + 4);
        float4 o0, o1;
        o0.x = x0.x + g0.x*bf2f(cp[0]); o0.y = x0.y + g0.y*bf2f(cp[1]);
        o0.z = x0.z + g0.z*bf2f(cp[2]); o0.w = x0.w + g0.w*bf2f(cp[3]);
        o1.x = x1.x + g1.x*bf2f(cp[4]); o1.y = x1.y + g1.y*bf2f(cp[5]);
        o1.z = x1.z + g1.z*bf2f(cp[6]); o1.w = x1.w + g1.w*bf2f(cp[7]);
        *(float4*)((float*)Cout + gbase)     = o0;
        *(float4*)((float*)Cout + gbase + 4) = o1;
      } else {
        const u16* xp = (const u16*)xres + gbase;
        const u16* gp = (const u16*)gammap + n0 + colb;
        u16 ov[8];
        #pragma unroll
        for (int k = 0; k < 8; ++k)
          ov[k] = f2bf(bf2f(xp[k]) + bf2f(gp[k]) * bf2f(cp[k]));
        *(bf16x8*)((u16*)Cout + gbase) = *(const bf16x8*)ov;
      }
    }
  }
}

// ---------------- deformable sampling: one wave per (b,q,h) ----------------
__global__ __launch_bounds__(256) void sample_kernel(
    const u16* __restrict__ value,   // [B*4096][768] bf16, col = h*128+d
    const float* __restrict__ offawp,// [2][8192][72] f32 K-partials
    const void* __restrict__ refp,   // [8192][2] external dtype
    u16* __restrict__ out, const int* __restrict__ flagp) {
  const int F = *flagp;
  const int wid  = blockIdx.x * 4 + (threadIdx.x >> 6);  // 0..49151
  const int lane = threadIdx.x & 63;
  const int h   = wid % 6;
  const int row = wid / 6;
  const int b   = row >> 12;
  const float* p0 = offawp + (size_t)row*72;
  const float* p1 = offawp + (size_t)NROWS*72 + (size_t)row*72;
  float ob[8], aw4[4];
  #pragma unroll
  for (int k = 0; k < 8; ++k) ob[k] = p0[h*8+k] + p1[h*8+k];
  #pragma unroll
  for (int k = 0; k < 4; ++k) aw4[k] = p0[48+h*4+k] + p1[48+h*4+k];
  float rx = ldf(refp, (size_t)row*2,   F) * 64.f - 0.5f;
  float ry = ldf(refp, (size_t)row*2+1, F) * 64.f - 0.5f;
  float mx = fmaxf(fmaxf(aw4[0],aw4[1]), fmaxf(aw4[2],aw4[3]));
  float e0 = __expf(aw4[0]-mx), e1 = __expf(aw4[1]-mx), e2 = __expf(aw4[2]-mx), e3 = __expf(aw4[3]-mx);
  float rs = 1.f / (e0+e1+e2+e3);
  float awt[4] = {e0*rs, e1*rs, e2*rs, e3*rs};
  const u32* vb = (const u32*)value + (size_t)b*4096*384 + h*64 + lane;
  float accx = 0.f, accy = 0.f;
  #pragma unroll
  for (int p = 0; p < 4; ++p) {
    float px = rx + ob[p*2];
    float py = ry + ob[p*2+1];
    float x0f = floorf(px), y0f = floorf(py);
    float fx = px - x0f, fy = py - y0f;
    int x0 = (int)x0f, y0 = (int)y0f;
    #pragma unroll
    for (int dy = 0; dy < 2; ++dy) {
      #pragma unroll
      for (int dx = 0; dx < 2; ++dx) {
        int yi = y0 + dy, xi = x0 + dx;
        float wt = (dy ? fy : 1.f-fy) * (dx ? fx : 1.f-fx) * awt[p];
        if (yi < 0 || yi >= 64 || xi < 0 || xi >= 64) wt = 0.f;
        if (wt != 0.f) {                       // wave-uniform
          u32 v = vb[(size_t)(yi*64 + xi) * 384];
          accx += wt * bf2f((u16)(v & 0xffffu));
          accy += wt * bf2f((u16)(v >> 16));
        }
      }
    }
  }
  ((u32*)out)[(size_t)row*384 + h*64 + lane] = (u32)f2bf(accx) | ((u32)f2bf(accy) << 16);
}

extern "C" void kernel_launch(void* const* d_in, const int* in_sizes, int n_in,
                              void* d_out, int out_size, void* d_ws, size_t ws_size,
                              hipStream_t stream) {
  const void* x       = d_in[0];
  const void* refp    = d_in[1];
  const void* feat    = d_in[2];
  const void* qn_w    = d_in[5];
  const void* qn_b    = d_in[6];
  const void* fn_w    = d_in[7];
  const void* fn_b    = d_in[8];
  const void* gamma   = d_in[9];
  const void* w_value = d_in[10];
  const void* b_value = d_in[11];
  const void* w_off   = d_in[12];
  const void* b_off   = d_in[13];
  const void* w_attn  = d_in[14];
  const void* b_attn  = d_in[15];
  const void* w_out   = d_in[16];
  const void* b_out   = d_in[17];

  char* p = (char*)d_ws;
  const size_t act = (size_t)NROWS * CDIM * 2;       // 12.58 MB
  u16* q_bf   = (u16*)p; p += act;
  u16* f_bf   = (u16*)p; p += act;
  u16* val_bf = (u16*)p; p += act;
  u16* wvT    = (u16*)p; p += (size_t)CDIM*CDIM*2;
  u16* woT    = (u16*)p; p += (size_t)CDIM*CDIM*2;
  u16* woaT   = (u16*)p; p += (size_t)128*CDIM*2;
  float* offawp = (float*)p; p += (size_t)2*NROWS*72*4;
  int* dflag  = (int*)p; p += 256;
  u16* samp_bf = q_bf;   // q_bf dead after gemm_bt<1>; reuse

  detect_kernel<<<dim3(1), 256, 0, stream>>>((const u16*)x, dflag);
  transpose_wt<<<dim3(24,24,2), 256, 0, stream>>>(w_value, w_out, wvT, woT, dflag);
  build_woffaw<<<dim3(384), 256, 0, stream>>>(w_off, w_attn, woaT, dflag);
  ln_kernel<<<dim3(16384), 192, 0, stream>>>(x, feat, qn_w, qn_b, fn_w, fn_b, q_bf, f_bf, dflag);
  gemm_bt<0><<<dim3(64,12,1), 256, 0, stream>>>(f_bf, wvT, val_bf, b_value, nullptr, nullptr, nullptr, dflag);
  gemm_bt<1><<<dim3(64,2,2),  256, 0, stream>>>(q_bf, woaT, offawp, b_off, b_attn, nullptr, nullptr, dflag);
  sample_kernel<<<dim3(12288), 256, 0, stream>>>(val_bf, offawp, refp, samp_bf, dflag);
  gemm_bt<2><<<dim3(64,12,1), 256, 0, stream>>>(samp_bf, woT, d_out, b_out, nullptr, x, gamma, dflag);
}